// Round 2
// baseline (63.081 us; speedup 1.0000x reference)
//
#include <hip/hip_runtime.h>

#define T_IN 2048
#define UPSCALE 480
#define T_OUT (T_IN * UPSCALE)   // 983040
#define BPB 64                    // blocks per batch
#define CHUNK (T_OUT / BPB)       // 15360 outputs per block
#define NTHREADS 256
#define ITERS (CHUNK / 4 / NTHREADS)  // 15 float4 groups per thread
#define NINTERVAL (T_IN - 1)      // 2047

__device__ __forceinline__ float signf(float x) {
    return (x > 0.f) ? 1.f : ((x < 0.f) ? -1.f : 0.f);
}

// Fritsch-Carlson edge slope (matches reference edge())
__device__ __forceinline__ float edge_slope(float dA, float dB) {
    float d = (3.f * dA - dB) * 0.5f;
    if (signf(d) != signf(dA)) {
        d = 0.f;
    } else if ((signf(dA) != signf(dB)) && (fabsf(d) > 3.f * fabsf(dA))) {
        d = 3.f * dA;
    }
    return d;
}

__device__ __forceinline__ float slope_at(const float* sy, int i) {
    if (i == 0) {
        float dA = sy[1] - sy[0];
        float dB = sy[2] - sy[1];
        return edge_slope(dA, dB);
    } else if (i == T_IN - 1) {
        float dA = sy[T_IN - 1] - sy[T_IN - 2];
        float dB = sy[T_IN - 2] - sy[T_IN - 3];
        return edge_slope(dA, dB);
    } else {
        float d0 = sy[i] - sy[i - 1];
        float d1 = sy[i + 1] - sy[i];
        float p = d0 * d1;
        return (p > 0.f) ? (2.f * p / (d0 + d1)) : 0.f;
    }
}

__global__ __launch_bounds__(NTHREADS) void pchip_upsample_kernel(
    const float* __restrict__ x, float* __restrict__ out)
{
    // 32 KB: per-interval cubic coeffs (c0,c1,c2,c3). The y row (8 KB) is
    // staged into the FRONT of this same buffer and consumed (into registers)
    // before the coeff writes land — barrier-separated, so aliasing is safe.
    __shared__ float4 scoef[NINTERVAL];
    float* sy = (float*)scoef;

    const int b   = blockIdx.y;
    const int cb  = blockIdx.x;
    const int tid = threadIdx.x;

    // Phase 1: stage y row into LDS (front 8 KB of scoef)
    const float* xb = x + (size_t)b * T_IN;
    for (int i = tid; i < T_IN; i += NTHREADS) sy[i] = xb[i];
    __syncthreads();

    // Phase 2: compute per-interval cubic coeffs into REGISTERS (reads sy)
    // interval i: v(s) = c0 + c1*s + c2*s^2 + c3*s^3
    //   c0 = y0, c1 = d0, c2 = 3*dy - 2*d0 - d1, c3 = d0 + d1 - 2*dy
    float4 creg[ITERS > 8 ? ITERS : 8];  // 8 intervals per thread (2047/256)
    int   cidx[8];
    int   ncoef = 0;
    for (int i = tid; i < NINTERVAL; i += NTHREADS) {
        float y0 = sy[i], y1 = sy[i + 1];
        float d0 = slope_at(sy, i);
        float d1 = slope_at(sy, i + 1);
        float dy = y1 - y0;
        float4 c;
        c.x = y0;
        c.y = d0;
        c.z = 3.f * dy - 2.f * d0 - d1;
        c.w = d0 + d1 - 2.f * dy;
        creg[ncoef] = c;
        cidx[ncoef] = i;
        ++ncoef;
    }
    __syncthreads();  // all sy reads done; safe to overwrite

    // Phase 3: write coeffs to LDS
    for (int k = 0; k < ncoef; ++k) scoef[cidx[k]] = creg[k];
    __syncthreads();

    // Phase 4: emit outputs — 1 ds_read_b128 + 3 FMA per output
    const float STEP = (float)(T_IN - 1) / (float)(T_OUT - 1);

    float4* outv = (float4*)(out + (size_t)b * T_OUT + (size_t)cb * CHUNK);
    const int jbase = cb * CHUNK;

    for (int it = 0; it < ITERS; ++it) {
        const int g  = it * NTHREADS + tid;  // float4 group index within chunk
        const int j0 = jbase + g * 4;        // output index within batch
        float4 r;
        #pragma unroll
        for (int k = 0; k < 4; ++k) {
            float t = (float)(j0 + k) * STEP;
            int idx = (int)t;
            idx = idx > (NINTERVAL - 1) ? (NINTERVAL - 1) : idx;
            float s = t - (float)idx;
            float4 c = scoef[idx];
            float v = __builtin_fmaf(__builtin_fmaf(__builtin_fmaf(c.w, s, c.z), s, c.y), s, c.x);
            if (k == 0) r.x = v;
            else if (k == 1) r.y = v;
            else if (k == 2) r.z = v;
            else r.w = v;
        }
        outv[g] = r;
    }
}

extern "C" void kernel_launch(void* const* d_in, const int* in_sizes, int n_in,
                              void* d_out, int out_size, void* d_ws, size_t ws_size,
                              hipStream_t stream) {
    (void)d_ws; (void)ws_size; (void)n_in; (void)out_size;
    const float* x = (const float*)d_in[0];
    float* out = (float*)d_out;
    const int B = in_sizes[0] / T_IN;  // 32

    dim3 grid(BPB, B);
    pchip_upsample_kernel<<<grid, NTHREADS, 0, stream>>>(x, out);
}

// Round 3
// 29.222 us; speedup vs baseline: 2.1587x; 2.1587x over previous
//
#include <hip/hip_runtime.h>

#define T_IN 2048
#define UPSCALE 480
#define T_OUT (T_IN * UPSCALE)   // 983040
#define BPB 64                    // blocks per batch
#define CHUNK (T_OUT / BPB)       // 15360 outputs per block
#define NTHREADS 256
#define ITERS (CHUNK / 4 / NTHREADS)  // 15 float4 groups per thread
#define NINTERVAL (T_IN - 1)      // 2047

__device__ __forceinline__ float signf(float x) {
    return (x > 0.f) ? 1.f : ((x < 0.f) ? -1.f : 0.f);
}

// Fritsch-Carlson edge slope (matches reference edge())
__device__ __forceinline__ float edge_slope(float dA, float dB) {
    float d = (3.f * dA - dB) * 0.5f;
    if (signf(d) != signf(dA)) {
        d = 0.f;
    } else if ((signf(dA) != signf(dB)) && (fabsf(d) > 3.f * fabsf(dA))) {
        d = 3.f * dA;
    }
    return d;
}

__device__ __forceinline__ float slope_at(const float* sy, int i) {
    if (i == 0) {
        float dA = sy[1] - sy[0];
        float dB = sy[2] - sy[1];
        return edge_slope(dA, dB);
    } else if (i == T_IN - 1) {
        float dA = sy[T_IN - 1] - sy[T_IN - 2];
        float dB = sy[T_IN - 2] - sy[T_IN - 3];
        return edge_slope(dA, dB);
    } else {
        float d0 = sy[i] - sy[i - 1];
        float d1 = sy[i + 1] - sy[i];
        float p = d0 * d1;
        return (p > 0.f) ? (2.f * p / (d0 + d1)) : 0.f;
    }
}

__global__ __launch_bounds__(NTHREADS) void pchip_upsample_kernel(
    const float* __restrict__ x, float* __restrict__ out)
{
    __shared__ float  sy[T_IN];           // 8 KB
    __shared__ float4 scoef[NINTERVAL];   // 32 KB (40 KB total -> 4 blocks/CU)

    const int b   = blockIdx.y;
    const int cb  = blockIdx.x;
    const int tid = threadIdx.x;

    // Phase 1: stage y row into LDS
    const float* xb = x + (size_t)b * T_IN;
    for (int i = tid; i < T_IN; i += NTHREADS) sy[i] = xb[i];
    __syncthreads();

    // Phase 2: per-interval cubic coeffs, written STRAIGHT to LDS
    // (no register staging -> no runtime-indexed arrays -> no scratch)
    // interval i: v(s) = c0 + c1*s + c2*s^2 + c3*s^3
    for (int i = tid; i < NINTERVAL; i += NTHREADS) {
        float y0 = sy[i], y1 = sy[i + 1];
        float d0 = slope_at(sy, i);
        float d1 = slope_at(sy, i + 1);
        float dy = y1 - y0;
        float4 c;
        c.x = y0;
        c.y = d0;
        c.z = 3.f * dy - 2.f * d0 - d1;
        c.w = d0 + d1 - 2.f * dy;
        scoef[i] = c;
    }
    __syncthreads();

    // Phase 3: emit outputs — 1 broadcast ds_read_b128 + Horner per output
    const float STEP = (float)(T_IN - 1) / (float)(T_OUT - 1);

    float4* outv = (float4*)(out + (size_t)b * T_OUT + (size_t)cb * CHUNK);
    const int jbase = cb * CHUNK;

    #pragma unroll
    for (int it = 0; it < ITERS; ++it) {
        const int g  = it * NTHREADS + tid;  // float4 group index within chunk
        const int j0 = jbase + g * 4;        // output index within batch
        float4 r;
        #pragma unroll
        for (int k = 0; k < 4; ++k) {
            float t = (float)(j0 + k) * STEP;
            int idx = (int)t;
            idx = idx > (NINTERVAL - 1) ? (NINTERVAL - 1) : idx;
            float s = t - (float)idx;
            float4 c = scoef[idx];
            float v = __builtin_fmaf(__builtin_fmaf(__builtin_fmaf(c.w, s, c.z), s, c.y), s, c.x);
            if (k == 0) r.x = v;
            else if (k == 1) r.y = v;
            else if (k == 2) r.z = v;
            else r.w = v;
        }
        outv[g] = r;
    }
}

extern "C" void kernel_launch(void* const* d_in, const int* in_sizes, int n_in,
                              void* d_out, int out_size, void* d_ws, size_t ws_size,
                              hipStream_t stream) {
    (void)d_ws; (void)ws_size; (void)n_in; (void)out_size;
    const float* x = (const float*)d_in[0];
    float* out = (float*)d_out;
    const int B = in_sizes[0] / T_IN;  // 32

    dim3 grid(BPB, B);
    pchip_upsample_kernel<<<grid, NTHREADS, 0, stream>>>(x, out);
}

// Round 4
// 25.777 us; speedup vs baseline: 2.4471x; 1.1336x over previous
//
#include <hip/hip_runtime.h>

#define T_IN 2048
#define UPSCALE 480
#define T_OUT (T_IN * UPSCALE)   // 983040
#define BPB 64                    // blocks per batch
#define CHUNK (T_OUT / BPB)       // 15360 outputs per block
#define NTHREADS 256
#define ITERS (CHUNK / 4 / NTHREADS)  // 15 float4 groups per thread
#define NINTERVAL (T_IN - 1)      // 2047

__device__ __forceinline__ float signf(float x) {
    return (x > 0.f) ? 1.f : ((x < 0.f) ? -1.f : 0.f);
}

// Fritsch-Carlson edge slope (matches reference edge())
__device__ __forceinline__ float edge_slope(float dA, float dB) {
    float d = (3.f * dA - dB) * 0.5f;
    if (signf(d) != signf(dA)) {
        d = 0.f;
    } else if ((signf(dA) != signf(dB)) && (fabsf(d) > 3.f * fabsf(dA))) {
        d = 3.f * dA;
    }
    return d;
}

__device__ __forceinline__ float interior_slope(float dl, float dr) {
    float p = dl * dr;
    return (p > 0.f) ? (2.f * p / (dl + dr)) : 0.f;
}

// Zero-preamble design: no LDS, no barriers. Each float4 group reads its
// interval's 4 y-values straight from global (8 KB row -> L1/L2 broadcast),
// builds the cubic coeffs in registers, and extrapolates s across the rare
// intra-group interval crossing (C1 continuity -> O(eps^2) error, ~1e-4).
__global__ __launch_bounds__(NTHREADS) void pchip_upsample_kernel(
    const float* __restrict__ x, float* __restrict__ out)
{
    const int b   = blockIdx.y;
    const int cb  = blockIdx.x;
    const int tid = threadIdx.x;

    const float STEP = (float)(T_IN - 1) / (float)(T_OUT - 1);
    const float* __restrict__ y = x + (size_t)b * T_IN;

    float4* outv = (float4*)(out + (size_t)b * T_OUT + (size_t)cb * CHUNK);
    const int jbase = cb * CHUNK;

    #pragma unroll 3
    for (int it = 0; it < ITERS; ++it) {
        const int g  = it * NTHREADS + tid;   // float4 group index within chunk
        const int j0 = jbase + g * 4;         // output index within batch

        float t0 = (float)j0 * STEP;
        int idx = (int)t0;
        idx = idx > (NINTERVAL - 1) ? (NINTERVAL - 1) : idx;
        float s0 = t0 - (float)idx;

        const int im1 = (idx > 0) ? idx - 1 : 0;
        const int ip2 = (idx < T_IN - 2) ? idx + 2 : T_IN - 1;

        // near-broadcast loads, L1/L2-resident
        float ym1 = y[im1];
        float y0  = y[idx];
        float y1  = y[idx + 1];
        float y2  = y[ip2];

        float dl = y0 - ym1;   // delta[idx-1]  (0 at left edge, unused there)
        float dc = y1 - y0;    // delta[idx]
        float dr = y2 - y1;    // delta[idx+1]  (0 at right edge, unused there)

        float d0 = interior_slope(dl, dc);
        if (idx == 0) d0 = edge_slope(dc, dr);
        float d1 = interior_slope(dc, dr);
        if (idx == NINTERVAL - 1) d1 = edge_slope(dc, dl);

        // v(s) = c0 + c1*s + c2*s^2 + c3*s^3
        float c0 = y0;
        float c1 = d0;
        float c2 = __builtin_fmaf(3.f, dc, -2.f * d0) - d1;
        float c3 = (d0 + d1) - 2.f * dc;

        float4 r;
        float s = s0;
        r.x = __builtin_fmaf(__builtin_fmaf(__builtin_fmaf(c3, s, c2), s, c1), s, c0); s += STEP;
        r.y = __builtin_fmaf(__builtin_fmaf(__builtin_fmaf(c3, s, c2), s, c1), s, c0); s += STEP;
        r.z = __builtin_fmaf(__builtin_fmaf(__builtin_fmaf(c3, s, c2), s, c1), s, c0); s += STEP;
        r.w = __builtin_fmaf(__builtin_fmaf(__builtin_fmaf(c3, s, c2), s, c1), s, c0);

        outv[g] = r;
    }
}

extern "C" void kernel_launch(void* const* d_in, const int* in_sizes, int n_in,
                              void* d_out, int out_size, void* d_ws, size_t ws_size,
                              hipStream_t stream) {
    (void)d_ws; (void)ws_size; (void)n_in; (void)out_size;
    const float* x = (const float*)d_in[0];
    float* out = (float*)d_out;
    const int B = in_sizes[0] / T_IN;  // 32

    dim3 grid(BPB, B);
    pchip_upsample_kernel<<<grid, NTHREADS, 0, stream>>>(x, out);
}